// Round 7
// baseline (170.125 us; speedup 1.0000x reference)
//
#include <hip/hip_runtime.h>
#include <hip/hip_bf16.h>
#include <stdint.h>

// Problem constants (fixed by reference): B=4,S=512 -> 2048 tokens, D=512, H=2048, E=8
#define D_DIM 512
#define H_DIM 2048
#define E_NUM 8
#define TM 64            // row-tile (padding granularity)
#define CAP 2560         // 2048 tokens + worst-case per-expert padding
#define MAXRT 6          // max row-tiles per expert (384 rows; ne~256±15, 8.5 sigma)

typedef __attribute__((ext_vector_type(8))) short short8;
typedef __attribute__((ext_vector_type(4))) float floatx4;

union Pack4 { short4 u; __hip_bfloat16 h[4]; };

// ---------------------------------------------------------------------------
// 1) Token binning. meta[0..7]=padded offset, [8..15]=ne, [16..23]=ntiles, [24]=total
__global__ __launch_bounds__(256) void bin_kernel(
    const int* __restrict__ orig, const int* __restrict__ hmap,
    int* __restrict__ gidx, int* __restrict__ meta, int ntok)
{
    __shared__ int cnt[E_NUM];
    __shared__ int cur[E_NUM];
    int tid = threadIdx.x;
    if (tid < E_NUM) cnt[tid] = 0;
    __syncthreads();
    for (int t = tid; t < ntok; t += 256) {
        int b = hmap[orig[t]];
        atomicAdd(&cnt[b], 1);
    }
    __syncthreads();
    if (tid == 0) {
        int off = 0;
        for (int e = 0; e < E_NUM; e++) {
            int ne = cnt[e];
            int nt = (ne + TM - 1) / TM;
            meta[e] = off; meta[8 + e] = ne; meta[16 + e] = nt;
            cur[e] = off;
            off += nt * TM;
        }
        meta[24] = off;
    }
    __syncthreads();
    for (int t = tid; t < ntok; t += 256) {
        int b = hmap[orig[t]];
        int p = atomicAdd(&cur[b], 1);
        gidx[p] = t;
    }
}

// ---------------------------------------------------------------------------
// 2) Gather x rows -> expert-sorted bf16 buffer; zero padding rows.
// (R10 fused this into gemm1 and regressed 9 µs: fp32 staging doubles bytes,
// scattered rows lose coalescing, +96 VGPR. Keep the separate gather.)
__global__ __launch_bounds__(128) void gather_kernel(
    const float* __restrict__ x, const int* __restrict__ gidx,
    const int* __restrict__ meta, __hip_bfloat16* __restrict__ Xg)
{
    int g = blockIdx.x;
    int e = -1, local = 0;
#pragma unroll
    for (int i = 0; i < E_NUM; i++) {
        int p = meta[i], nt = meta[16 + i];
        if (g >= p && g < p + nt * TM) { e = i; local = g - p; }
    }
    if (e < 0) return;
    int tid = threadIdx.x;
    __hip_bfloat16* orow = Xg + (size_t)g * D_DIM + tid * 4;
    if (local < meta[8 + e]) {
        int t = gidx[g];
        float4 v = ((const float4*)(x + (size_t)t * D_DIM))[tid];
        orow[0] = __float2bfloat16(v.x);
        orow[1] = __float2bfloat16(v.y);
        orow[2] = __float2bfloat16(v.z);
        orow[3] = __float2bfloat16(v.w);
    } else {
        orow[0] = __float2bfloat16(0.f);
        orow[1] = __float2bfloat16(0.f);
        orow[2] = __float2bfloat16(0.f);
        orow[3] = __float2bfloat16(0.f);
    }
}

// ---------------------------------------------------------------------------
// 3) Expert-column MoE GEMM (R9 champion pipeline; R15 occupancy fix).
// R15: both instantiations now launch 512 blocks -> 2 blocks/CU (2 waves/SIMD)
// WITHOUT duplicating the dominant W stream (R12's fatal mistake):
//   GEMM1: column tile NT=32 (disjoint W1 n-slices), grid 64n x 8e.
//   GEMM2: split-K=8 (disjoint W2/Hb k-slices), grid 8n x 8ks x 8e.
// At 1 block/CU the 4 waves are barrier-locked and every vmcnt stall is
// exposed; a second independent resident block fills those stalls.
// __launch_bounds__(256,2) caps VGPR at 256 to guarantee residency.
// A staged via register round-trip (global->VGPR->ds_write): private vmem
// loads are NOT drained by __syncthreads, so A(i+1)/B(i+1) loads issued
// before compute(i) stay in flight across the barrier pair; their vmcnt wait
// lands at the ds_write one full iteration later -> hidden behind compute.
//   A  [CAP, ASTRIDE] bf16 expert-sorted;  W [E][KTOT][WN] fp32 (fused cvt+transpose)
//   RELU: OutBf = bf16(relu(acc + bias));  else OutP[ks][CAP][WN] bf16 partials
// LDS: As [384 x 64k] bf16 48 KB (phys chunk c=(row*8+q): byte c*16 holds
//      src k-bytes (q*16)^((row&7)*16) -> conflict-free b128 reads/writes),
//      Bs [NT n x 64k] bf16 (phys(n,kb)=n*128+(kb^(((n>>2)&7)*16)))
// Wave tiling: NT=64 -> 2x2 wave grid (champion); NT=32 -> 4x1 row strips.
template <int WN, int NT, int ASTRIDE, int KTOT, int KS, bool RELU>
__global__ __launch_bounds__(256, 2) void moe_gemm_kernel(
    const __hip_bfloat16* __restrict__ A,
    const float* __restrict__ W,
    const float* __restrict__ bias,
    __hip_bfloat16* __restrict__ OutBf,   // RELU: full output
    __hip_bfloat16* __restrict__ OutP,    // !RELU: bf16 split-K partials
    const int* __restrict__ meta)
{
    static_assert(NT == 32 || NT == 64, "NT must be 32 or 64");
    constexpr int KLEN = KTOT / KS;           // 512 (GEMM1) / 256 (GEMM2)
    constexpr int NI = KLEN / 64;             // 8 / 4 k-iterations
    constexpr int AJ = MAXRT * 64 * 8 / 256;  // 12 A-chunks (16B) per thread max
    constexpr int NWC = NT / 32;              // wave-cols (2 or 1)
    constexpr int RW = 16 * NWC;              // rows per wave within a 64-row rt
    constexpr int BT = 4 * NT;                // threads active in B staging
    const int e = blockIdx.z;
    const int n0 = blockIdx.x * NT;
    const int ks = blockIdx.y;
    const int kbase = ks * KLEN;

    int nt = meta[16 + e];
    if (nt > MAXRT) nt = MAXRT;
    const int row0 = meta[e];
    const int rows8 = nt * 64 * 8;            // active 16B chunks in A stage

    __shared__ __align__(16) __hip_bfloat16 As[384 * 64];   // 48 KB
    __shared__ __align__(16) __hip_bfloat16 Bs[NT * 64];    // 8 / 4 KB

    const int tid = threadIdx.x;
    const int lane = tid & 63, w = tid >> 6;
    const int quad = lane >> 4, l16 = lane & 15;
    const int wr = w / NWC, wc = w % NWC;     // wave grid over 64 x NT tile
    const int kq = tid / (NT / 4);            // B staging: 4 k-rows per thread
    const int nb = tid & (NT / 4 - 1);        // B staging: 4 n-cols per thread

    const __hip_bfloat16* Ab = A + (size_t)row0 * ASTRIDE + kbase;
    const float* Wb = W + ((size_t)e * KTOT + kbase) * WN + n0;

    floatx4 acc[MAXRT][NWC][2] = {};          // 96 (NT=64) / 48 (NT=32) VGPRs
    short8 ar[AJ];    // A prefetch registers (48 VGPRs)
    float4 br[4];     // B prefetch registers (16 VGPRs)

#define LOADA(k0) do {                                                        \
    _Pragma("unroll")                                                         \
    for (int j = 0; j < AJ; j++) {                                            \
        int c = tid + j * 256;                                                \
        if (c < rows8) {                                                      \
            int row = c >> 3;                                                 \
            int kk = ((c & 7) * 16) ^ ((row & 7) * 16);   /* bytes */         \
            ar[j] = *(const short8*)(Ab + (size_t)row * ASTRIDE + (k0) + (kk >> 1)); \
        }                                                                     \
    }                                                                         \
} while (0)

#define WRITEA() do {                                                         \
    _Pragma("unroll")                                                         \
    for (int j = 0; j < AJ; j++) {                                            \
        int c = tid + j * 256;                                                \
        if (c < rows8)                                                        \
            *(short8*)((char*)As + c * 16) = ar[j];                           \
    }                                                                         \
} while (0)

#define LOADB(k0) do {                                                        \
    if (tid < BT) {                                                           \
        _Pragma("unroll")                                                     \
        for (int r = 0; r < 4; r++)                                           \
            br[r] = *(const float4*)(Wb + (size_t)((k0) + kq * 4 + r) * WN + nb * 4); \
    }                                                                         \
} while (0)

#define WRITEB() do {                                                         \
    if (tid < BT) {                                                           \
        _Pragma("unroll")                                                     \
        for (int j = 0; j < 4; j++) {                                         \
            int n = nb * 4 + j;                                               \
            Pack4 pk;                                                         \
            _Pragma("unroll")                                                 \
            for (int r = 0; r < 4; r++)                                       \
                pk.h[r] = __float2bfloat16(reinterpret_cast<const float*>(&br[r])[j]); \
            *(short4*)((char*)Bs + n * 128 + ((kq * 8) ^ (((n >> 2) & 7) * 16))) = pk.u; \
        }                                                                     \
    }                                                                         \
} while (0)

    LOADA(0);
    LOADB(0);

    for (int i = 0; i < NI; i++) {
        __syncthreads();    // prior iter's LDS reads complete
        WRITEA();           // vmcnt wait for loads issued one iter ago lands here
        WRITEB();
        __syncthreads();
        if (i + 1 < NI) {   // issue next-iter loads; they fly across the barriers
            LOADA((i + 1) * 64);
            LOADB((i + 1) * 64);
        }
#pragma unroll
        for (int kf = 0; kf < 2; kf++) {
            int kb = kf * 64 + quad * 16;
            short8 b[2];
#pragma unroll
            for (int ni = 0; ni < 2; ni++) {
                int n = wc * 32 + ni * 16 + l16;
                b[ni] = *(const short8*)((char*)Bs + n * 128 + (kb ^ (((n >> 2) & 7) * 16)));
            }
#pragma unroll
            for (int rt = 0; rt < MAXRT; rt++) {
                if (rt < nt) {
                    short8 a[NWC];
#pragma unroll
                    for (int mi = 0; mi < NWC; mi++) {
                        int row = rt * 64 + wr * RW + mi * 16 + l16;
                        a[mi] = *(const short8*)((char*)As + row * 128 + (kb ^ ((row & 7) * 16)));
                    }
#pragma unroll
                    for (int mi = 0; mi < NWC; mi++)
#pragma unroll
                        for (int ni = 0; ni < 2; ni++)
                            acc[rt][mi][ni] = __builtin_amdgcn_mfma_f32_16x16x32_bf16(
                                a[mi], b[ni], acc[rt][mi][ni], 0, 0, 0);
                }
            }
        }
    }

    // Epilogue. C/D layout (m89-verified): col = lane&15, row = (lane>>4)*4 + reg
#pragma unroll
    for (int rt = 0; rt < MAXRT; rt++) {
        if (rt >= nt) break;
#pragma unroll
        for (int ni = 0; ni < 2; ni++) {
            int col = n0 + wc * 32 + ni * 16 + l16;
            float bv = RELU ? bias[e * WN + col] : 0.f;
#pragma unroll
            for (int mi = 0; mi < NWC; mi++) {
#pragma unroll
                for (int r = 0; r < 4; r++) {
                    int grow = row0 + rt * 64 + wr * RW + mi * 16 + quad * 4 + r;
                    float v = acc[rt][mi][ni][r] + bv;
                    if constexpr (RELU) {
                        v = v > 0.f ? v : 0.f;
                        OutBf[(size_t)grow * WN + col] = __float2bfloat16(v);
                    } else {
                        OutP[((size_t)ks * CAP + grow) * WN + col] = __float2bfloat16(v);
                    }
                }
            }
        }
    }
#undef LOADA
#undef WRITEA
#undef LOADB
#undef WRITEB
}

// ---------------------------------------------------------------------------
// 4) Residual + b2 + 8-way bf16 split-K sum + LayerNorm, scatter to token order.
__global__ __launch_bounds__(128) void ln_kernel(
    const float* __restrict__ x, const __hip_bfloat16* __restrict__ Yp,
    const float* __restrict__ b2,
    const float* __restrict__ gamma, const float* __restrict__ beta,
    const int* __restrict__ gidx, const int* __restrict__ meta,
    float* __restrict__ out)
{
    int g = blockIdx.x;
    int e = -1;
#pragma unroll
    for (int i = 0; i < E_NUM; i++) {
        int p = meta[i], ne = meta[8 + i];
        if (g >= p && g - p < ne) e = i;
    }
    if (e < 0) return;   // padding row or beyond total
    int t = gidx[g];
    int tid = threadIdx.x;

    float4 xv = ((const float4*)(x + (size_t)t * D_DIM))[tid];
    float4 bb = ((const float4*)(b2 + (size_t)e * D_DIM))[tid];
    float z0 = xv.x + bb.x, z1 = xv.y + bb.y, z2 = xv.z + bb.z, z3 = xv.w + bb.w;
#pragma unroll
    for (int s4 = 0; s4 < 8; s4++) {
        union { short4 u; __hip_bfloat16 h[4]; } yv;
        yv.u = ((const short4*)(Yp + (size_t)(s4 * CAP + g) * D_DIM))[tid];
        z0 += __bfloat162float(yv.h[0]);
        z1 += __bfloat162float(yv.h[1]);
        z2 += __bfloat162float(yv.h[2]);
        z3 += __bfloat162float(yv.h[3]);
    }

    float s = z0 + z1 + z2 + z3;
    float ss = z0 * z0 + z1 * z1 + z2 * z2 + z3 * z3;
#pragma unroll
    for (int off = 32; off > 0; off >>= 1) {
        s  += __shfl_down(s, off, 64);
        ss += __shfl_down(ss, off, 64);
    }
    __shared__ float red[4];
    int lane = tid & 63, wv = tid >> 6;
    if (lane == 0) { red[wv] = s; red[2 + wv] = ss; }
    __syncthreads();
    float S = red[0] + red[1];
    float SS = red[2] + red[3];
    float mu = S * (1.f / D_DIM);
    float var = SS * (1.f / D_DIM) - mu * mu;
    float inv = rsqrtf(var + 1e-5f);

    float4 gv = ((const float4*)gamma)[tid];
    float4 bv = ((const float4*)beta)[tid];
    float4 o;
    o.x = (z0 - mu) * inv * gv.x + bv.x;
    o.y = (z1 - mu) * inv * gv.y + bv.y;
    o.z = (z2 - mu) * inv * gv.z + bv.z;
    o.w = (z3 - mu) * inv * gv.w + bv.w;
    ((float4*)(out + (size_t)t * D_DIM))[tid] = o;
}

// ---------------------------------------------------------------------------
extern "C" void kernel_launch(void* const* d_in, const int* in_sizes, int n_in,
                              void* d_out, int out_size, void* d_ws, size_t ws_size,
                              hipStream_t stream)
{
    const float* x     = (const float*)d_in[0];
    const float* W1    = (const float*)d_in[1];
    const float* b1    = (const float*)d_in[2];
    const float* W2    = (const float*)d_in[3];
    const float* b2    = (const float*)d_in[4];
    const float* gamma = (const float*)d_in[5];
    const float* beta  = (const float*)d_in[6];
    const int* orig    = (const int*)d_in[7];
    const int* hmap    = (const int*)d_in[8];
    float* out = (float*)d_out;
    int ntok = in_sizes[7];   // B*S = 2048

    // Workspace layout (~34.1 MB)
    char* ws = (char*)d_ws;
    __hip_bfloat16* Yp  = (__hip_bfloat16*)(ws);             // [8][CAP][512] bf16, 20.97 MB
    __hip_bfloat16* Hb  = (__hip_bfloat16*)(ws + 20971520);  // [CAP][2048] bf16, 10.49 MB
    __hip_bfloat16* Xg  = (__hip_bfloat16*)(ws + 31457280);  // [CAP][512] bf16, 2.62 MB
    int*            gidx= (int*)(ws + 34078720);             // [CAP]
    int*            meta= (int*)(ws + 34088960);             // 32 ints

    hipLaunchKernelGGL(bin_kernel, dim3(1), dim3(256), 0, stream,
                       orig, hmap, gidx, meta, ntok);
    hipLaunchKernelGGL(gather_kernel, dim3(CAP), dim3(128), 0, stream,
                       x, gidx, meta, Xg);
    // GEMM1: Xg[rows,512] x W1[E][512][2048] -> relu(+b1) -> bf16 Hb.
    // NT=32: grid (64 n, 1, 8 e) = 512 blocks -> 2 blocks/CU, W1 read once.
    hipLaunchKernelGGL((moe_gemm_kernel<H_DIM, 32, D_DIM, D_DIM, 1, true>),
                       dim3(H_DIM / 32, 1, E_NUM), dim3(256), 0, stream,
                       Xg, W1, b1, Hb, (__hip_bfloat16*)nullptr, meta);
    // GEMM2: Hb[rows,2048] x W2[E][2048][512] -> bf16 partials (split-K=8).
    // grid (8 n, 8 ks, 8 e) = 512 blocks -> 2 blocks/CU, W2 read once.
    hipLaunchKernelGGL((moe_gemm_kernel<D_DIM, 64, H_DIM, H_DIM, 8, false>),
                       dim3(D_DIM / 64, 8, E_NUM), dim3(256), 0, stream,
                       Hb, W2, (const float*)nullptr, (__hip_bfloat16*)nullptr, Yp, meta);
    hipLaunchKernelGGL(ln_kernel, dim3(CAP), dim3(128), 0, stream,
                       x, Yp, b2, gamma, beta, gidx, meta, out);
}

// Round 8
// 150.024 us; speedup vs baseline: 1.1340x; 1.1340x over previous
//
#include <hip/hip_runtime.h>
#include <hip/hip_bf16.h>
#include <stdint.h>

// Problem constants (fixed by reference): B=4,S=512 -> 2048 tokens, D=512, H=2048, E=8
#define D_DIM 512
#define H_DIM 2048
#define E_NUM 8
#define TM 64            // row-tile (padding granularity)
#define CAP 2560         // 2048 tokens + worst-case per-expert padding
#define MAXRT 6          // max row-tiles per expert (384 rows; ne~256±15, 8.5 sigma)

typedef __attribute__((ext_vector_type(8))) short short8;
typedef __attribute__((ext_vector_type(4))) float floatx4;

union Pack4 { short4 u; __hip_bfloat16 h[4]; };

// ---------------------------------------------------------------------------
// 1) Token binning. meta[0..7]=padded offset, [8..15]=ne, [16..23]=ntiles, [24]=total
// R16: 1024 threads (was 256). bin is 1 block; its two passes are chains of
// dependent global loads (orig[t] -> random hmap[orig[t]]) with 255 CUs idle.
// 4x thread parallelism cuts the serial-latency iterations 8 -> 2 per pass.
__global__ __launch_bounds__(1024) void bin_kernel(
    const int* __restrict__ orig, const int* __restrict__ hmap,
    int* __restrict__ gidx, int* __restrict__ meta, int ntok)
{
    __shared__ int cnt[E_NUM];
    __shared__ int cur[E_NUM];
    int tid = threadIdx.x;
    if (tid < E_NUM) cnt[tid] = 0;
    __syncthreads();
    for (int t = tid; t < ntok; t += 1024) {
        int b = hmap[orig[t]];
        atomicAdd(&cnt[b], 1);
    }
    __syncthreads();
    if (tid == 0) {
        int off = 0;
        for (int e = 0; e < E_NUM; e++) {
            int ne = cnt[e];
            int nt = (ne + TM - 1) / TM;
            meta[e] = off; meta[8 + e] = ne; meta[16 + e] = nt;
            cur[e] = off;
            off += nt * TM;
        }
        meta[24] = off;
    }
    __syncthreads();
    for (int t = tid; t < ntok; t += 1024) {
        int b = hmap[orig[t]];
        int p = atomicAdd(&cur[b], 1);
        gidx[p] = t;
    }
}

// ---------------------------------------------------------------------------
// 2) Gather x rows -> expert-sorted bf16 buffer; zero padding rows.
// (R10 fused this into gemm1 and regressed 9 µs: fp32 staging doubles bytes,
// scattered rows lose coalescing, +96 VGPR. Keep the separate gather.)
__global__ __launch_bounds__(128) void gather_kernel(
    const float* __restrict__ x, const int* __restrict__ gidx,
    const int* __restrict__ meta, __hip_bfloat16* __restrict__ Xg)
{
    int g = blockIdx.x;
    int e = -1, local = 0;
#pragma unroll
    for (int i = 0; i < E_NUM; i++) {
        int p = meta[i], nt = meta[16 + i];
        if (g >= p && g < p + nt * TM) { e = i; local = g - p; }
    }
    if (e < 0) return;
    int tid = threadIdx.x;
    __hip_bfloat16* orow = Xg + (size_t)g * D_DIM + tid * 4;
    if (local < meta[8 + e]) {
        int t = gidx[g];
        float4 v = ((const float4*)(x + (size_t)t * D_DIM))[tid];
        orow[0] = __float2bfloat16(v.x);
        orow[1] = __float2bfloat16(v.y);
        orow[2] = __float2bfloat16(v.z);
        orow[3] = __float2bfloat16(v.w);
    } else {
        orow[0] = __float2bfloat16(0.f);
        orow[1] = __float2bfloat16(0.f);
        orow[2] = __float2bfloat16(0.f);
        orow[3] = __float2bfloat16(0.f);
    }
}

// ---------------------------------------------------------------------------
// 3) Expert-column MoE GEMM (R9 champion, byte-identical). A staged via
// register round-trip (global->VGPR->ds_write): private vmem loads are NOT
// drained by __syncthreads (unlike global_load_lds DMA, which hits the
// compiler's vmcnt(0)-before-barrier rule), so A(i+1)/B(i+1) loads issued
// before compute(i) stay in flight across the barrier pair; their vmcnt wait
// lands at the ds_write one full iteration later -> hidden behind compute.
// Five structural perturbations (R10-R15) all regressed 8-18 µs: fused
// gather, 4x1 wave tiling, row-split grid, 2-deep prefetch, NT=32/KS=8
// occupancy raise (confounded by (256,2) VGPR cap). Do not perturb blind.
//   A  [CAP, ASTRIDE] bf16 expert-sorted;  W [E][KTOT][WN] fp32 (fused cvt+transpose)
//   RELU: OutBf = bf16(relu(acc + bias));  else OutP[ks][CAP][WN] bf16 partials
// LDS: As [384 x 64k] bf16 48 KB (phys chunk c=(row*8+q): byte c*16 holds
//      src k-bytes (q*16)^((row&7)*16) -> conflict-free b128 reads/writes),
//      Bs [64n x 64k] bf16 8 KB (phys(n,kb)=n*128+(kb^(((n>>2)&7)*16)))
template <int WN, int ASTRIDE, int KTOT, int KS, bool RELU>
__global__ __launch_bounds__(256) void moe_gemm_kernel(
    const __hip_bfloat16* __restrict__ A,
    const float* __restrict__ W,
    const float* __restrict__ bias,
    __hip_bfloat16* __restrict__ OutBf,   // RELU: full output
    __hip_bfloat16* __restrict__ OutP,    // !RELU: bf16 split-K partials
    const int* __restrict__ meta)
{
    constexpr int KLEN = KTOT / KS;           // 512 in both instantiations
    constexpr int NI = KLEN / 64;             // 8 k-iterations
    constexpr int AJ = MAXRT * 64 * 8 / 256;  // 12 A-chunks (16B) per thread max
    const int e = blockIdx.z;
    const int n0 = blockIdx.x * 64;
    const int ks = blockIdx.y;
    const int kbase = ks * KLEN;

    int nt = meta[16 + e];
    if (nt > MAXRT) nt = MAXRT;
    const int row0 = meta[e];
    const int rows8 = nt * 64 * 8;            // active 16B chunks in A stage

    __shared__ __align__(16) __hip_bfloat16 As[384 * 64];   // 48 KB
    __shared__ __align__(16) __hip_bfloat16 Bs[64 * 64];    // 8 KB

    const int tid = threadIdx.x;
    const int lane = tid & 63, w = tid >> 6;
    const int quad = lane >> 4, l16 = lane & 15;
    const int wr = w >> 1, wc = w & 1;        // 2x2 wave grid per 64x64 tile
    const int kq = tid >> 4;                  // B staging: 4 k-rows
    const int nb = tid & 15;                  // B staging: 4 n-cols

    const __hip_bfloat16* Ab = A + (size_t)row0 * ASTRIDE + kbase;
    const float* Wb = W + ((size_t)e * KTOT + kbase) * WN + n0;

    floatx4 acc[MAXRT][2][2] = {};
    short8 ar[AJ];    // A prefetch registers (48 VGPRs)
    float4 br[4];     // B prefetch registers (16 VGPRs)

#define LOADA(k0) do {                                                        \
    _Pragma("unroll")                                                         \
    for (int j = 0; j < AJ; j++) {                                            \
        int c = tid + j * 256;                                                \
        if (c < rows8) {                                                      \
            int row = c >> 3;                                                 \
            int kk = ((c & 7) * 16) ^ ((row & 7) * 16);   /* bytes */         \
            ar[j] = *(const short8*)(Ab + (size_t)row * ASTRIDE + (k0) + (kk >> 1)); \
        }                                                                     \
    }                                                                         \
} while (0)

#define WRITEA() do {                                                         \
    _Pragma("unroll")                                                         \
    for (int j = 0; j < AJ; j++) {                                            \
        int c = tid + j * 256;                                                \
        if (c < rows8)                                                        \
            *(short8*)((char*)As + c * 16) = ar[j];                           \
    }                                                                         \
} while (0)

#define LOADB(k0) do {                                                        \
    _Pragma("unroll")                                                         \
    for (int r = 0; r < 4; r++)                                               \
        br[r] = *(const float4*)(Wb + (size_t)((k0) + kq * 4 + r) * WN + nb * 4); \
} while (0)

#define WRITEB() do {                                                         \
    _Pragma("unroll")                                                         \
    for (int j = 0; j < 4; j++) {                                             \
        int n = nb * 4 + j;                                                   \
        Pack4 pk;                                                             \
        _Pragma("unroll")                                                     \
        for (int r = 0; r < 4; r++)                                           \
            pk.h[r] = __float2bfloat16(reinterpret_cast<const float*>(&br[r])[j]); \
        *(short4*)((char*)Bs + n * 128 + ((kq * 8) ^ (((n >> 2) & 7) * 16))) = pk.u; \
    }                                                                         \
} while (0)

    LOADA(0);
    LOADB(0);

    for (int i = 0; i < NI; i++) {
        __syncthreads();    // prior iter's LDS reads complete
        WRITEA();           // vmcnt wait for loads issued one iter ago lands here
        WRITEB();
        __syncthreads();
        if (i + 1 < NI) {   // issue next-iter loads; they fly across the barriers
            LOADA((i + 1) * 64);
            LOADB((i + 1) * 64);
        }
#pragma unroll
        for (int kf = 0; kf < 2; kf++) {
            int kb = kf * 64 + quad * 16;
            short8 b[2];
#pragma unroll
            for (int ni = 0; ni < 2; ni++) {
                int n = wc * 32 + ni * 16 + l16;
                b[ni] = *(const short8*)((char*)Bs + n * 128 + (kb ^ (((n >> 2) & 7) * 16)));
            }
#pragma unroll
            for (int rt = 0; rt < MAXRT; rt++) {
                if (rt < nt) {
                    short8 a[2];
#pragma unroll
                    for (int mi = 0; mi < 2; mi++) {
                        int row = rt * 64 + wr * 32 + mi * 16 + l16;
                        a[mi] = *(const short8*)((char*)As + row * 128 + (kb ^ ((row & 7) * 16)));
                    }
#pragma unroll
                    for (int mi = 0; mi < 2; mi++)
#pragma unroll
                        for (int ni = 0; ni < 2; ni++)
                            acc[rt][mi][ni] = __builtin_amdgcn_mfma_f32_16x16x32_bf16(
                                a[mi], b[ni], acc[rt][mi][ni], 0, 0, 0);
                }
            }
        }
    }

    // Epilogue. C/D layout (m89-verified): col = lane&15, row = (lane>>4)*4 + reg
#pragma unroll
    for (int rt = 0; rt < MAXRT; rt++) {
        if (rt >= nt) break;
#pragma unroll
        for (int ni = 0; ni < 2; ni++) {
            int col = n0 + wc * 32 + ni * 16 + l16;
            float bv = RELU ? bias[e * WN + col] : 0.f;
#pragma unroll
            for (int mi = 0; mi < 2; mi++) {
#pragma unroll
                for (int r = 0; r < 4; r++) {
                    int grow = row0 + rt * 64 + wr * 32 + mi * 16 + quad * 4 + r;
                    float v = acc[rt][mi][ni][r] + bv;
                    if constexpr (RELU) {
                        v = v > 0.f ? v : 0.f;
                        OutBf[(size_t)grow * WN + col] = __float2bfloat16(v);
                    } else {
                        OutP[((size_t)ks * CAP + grow) * WN + col] = __float2bfloat16(v);
                    }
                }
            }
        }
    }
#undef LOADA
#undef WRITEA
#undef LOADB
#undef WRITEB
}

// ---------------------------------------------------------------------------
// 4) Residual + b2 + 4-way bf16 split-K sum + LayerNorm, scatter to token order.
__global__ __launch_bounds__(128) void ln_kernel(
    const float* __restrict__ x, const __hip_bfloat16* __restrict__ Yp,
    const float* __restrict__ b2,
    const float* __restrict__ gamma, const float* __restrict__ beta,
    const int* __restrict__ gidx, const int* __restrict__ meta,
    float* __restrict__ out)
{
    int g = blockIdx.x;
    int e = -1;
#pragma unroll
    for (int i = 0; i < E_NUM; i++) {
        int p = meta[i], ne = meta[8 + i];
        if (g >= p && g - p < ne) e = i;
    }
    if (e < 0) return;   // padding row or beyond total
    int t = gidx[g];
    int tid = threadIdx.x;

    float4 xv = ((const float4*)(x + (size_t)t * D_DIM))[tid];
    float4 bb = ((const float4*)(b2 + (size_t)e * D_DIM))[tid];
    float z0 = xv.x + bb.x, z1 = xv.y + bb.y, z2 = xv.z + bb.z, z3 = xv.w + bb.w;
#pragma unroll
    for (int s4 = 0; s4 < 4; s4++) {
        union { short4 u; __hip_bfloat16 h[4]; } yv;
        yv.u = ((const short4*)(Yp + (size_t)(s4 * CAP + g) * D_DIM))[tid];
        z0 += __bfloat162float(yv.h[0]);
        z1 += __bfloat162float(yv.h[1]);
        z2 += __bfloat162float(yv.h[2]);
        z3 += __bfloat162float(yv.h[3]);
    }

    float s = z0 + z1 + z2 + z3;
    float ss = z0 * z0 + z1 * z1 + z2 * z2 + z3 * z3;
#pragma unroll
    for (int off = 32; off > 0; off >>= 1) {
        s  += __shfl_down(s, off, 64);
        ss += __shfl_down(ss, off, 64);
    }
    __shared__ float red[4];
    int lane = tid & 63, wv = tid >> 6;
    if (lane == 0) { red[wv] = s; red[2 + wv] = ss; }
    __syncthreads();
    float S = red[0] + red[1];
    float SS = red[2] + red[3];
    float mu = S * (1.f / D_DIM);
    float var = SS * (1.f / D_DIM) - mu * mu;
    float inv = rsqrtf(var + 1e-5f);

    float4 gv = ((const float4*)gamma)[tid];
    float4 bv = ((const float4*)beta)[tid];
    float4 o;
    o.x = (z0 - mu) * inv * gv.x + bv.x;
    o.y = (z1 - mu) * inv * gv.y + bv.y;
    o.z = (z2 - mu) * inv * gv.z + bv.z;
    o.w = (z3 - mu) * inv * gv.w + bv.w;
    ((float4*)(out + (size_t)t * D_DIM))[tid] = o;
}

// ---------------------------------------------------------------------------
extern "C" void kernel_launch(void* const* d_in, const int* in_sizes, int n_in,
                              void* d_out, int out_size, void* d_ws, size_t ws_size,
                              hipStream_t stream)
{
    const float* x     = (const float*)d_in[0];
    const float* W1    = (const float*)d_in[1];
    const float* b1    = (const float*)d_in[2];
    const float* W2    = (const float*)d_in[3];
    const float* b2    = (const float*)d_in[4];
    const float* gamma = (const float*)d_in[5];
    const float* beta  = (const float*)d_in[6];
    const int* orig    = (const int*)d_in[7];
    const int* hmap    = (const int*)d_in[8];
    float* out = (float*)d_out;
    int ntok = in_sizes[7];   // B*S = 2048

    // Workspace layout (~23.6 MB)
    char* ws = (char*)d_ws;
    __hip_bfloat16* Yp  = (__hip_bfloat16*)(ws);             // [4][CAP][512] bf16, 10.49 MB
    __hip_bfloat16* Hb  = (__hip_bfloat16*)(ws + 10485760);  // [CAP][2048] bf16, 10.49 MB
    __hip_bfloat16* Xg  = (__hip_bfloat16*)(ws + 20971520);  // [CAP][512] bf16, 2.62 MB
    int*            gidx= (int*)(ws + 23592960);             // [CAP]
    int*            meta= (int*)(ws + 23603200);             // 32 ints

    hipLaunchKernelGGL(bin_kernel, dim3(1), dim3(1024), 0, stream,
                       orig, hmap, gidx, meta, ntok);
    hipLaunchKernelGGL(gather_kernel, dim3(CAP), dim3(128), 0, stream,
                       x, gidx, meta, Xg);
    // GEMM1: Xg[rows,512] x W1[E][512][2048] -> relu(+b1) -> bf16 Hb. grid 256.
    hipLaunchKernelGGL((moe_gemm_kernel<H_DIM, D_DIM, D_DIM, 1, true>),
                       dim3(H_DIM / 64, 1, E_NUM), dim3(256), 0, stream,
                       Xg, W1, b1, Hb, (__hip_bfloat16*)nullptr, meta);
    // GEMM2: Hb[rows,2048] x W2[E][2048][512] -> bf16 partials (split-K=4). grid 256.
    hipLaunchKernelGGL((moe_gemm_kernel<D_DIM, H_DIM, H_DIM, 4, false>),
                       dim3(D_DIM / 64, 4, E_NUM), dim3(256), 0, stream,
                       Hb, W2, (const float*)nullptr, (__hip_bfloat16*)nullptr, Yp, meta);
    hipLaunchKernelGGL(ln_kernel, dim3(CAP), dim3(128), 0, stream,
                       x, Yp, b2, gamma, beta, gidx, meta, out);
}

// Round 9
// 149.259 us; speedup vs baseline: 1.1398x; 1.0051x over previous
//
#include <hip/hip_runtime.h>
#include <hip/hip_bf16.h>
#include <stdint.h>

// Problem constants (fixed by reference): B=4,S=512 -> 2048 tokens, D=512, H=2048, E=8
#define D_DIM 512
#define H_DIM 2048
#define E_NUM 8
#define TM 64            // row-tile (padding granularity)
#define CAP 2560         // 2048 tokens + worst-case per-expert padding
#define MAXRT 6          // max row-tiles per expert (384 rows; ne~256±15, 8.5 sigma)

typedef __attribute__((ext_vector_type(8))) short short8;
typedef __attribute__((ext_vector_type(4))) float floatx4;

union Pack4 { short4 u; __hip_bfloat16 h[4]; };

// ---------------------------------------------------------------------------
// 1) Token binning. meta[0..7]=padded offset, [8..15]=ne, [16..23]=ntiles, [24]=total
// R16: 1024 threads. bin is 1 block; its two passes are chains of dependent
// global loads (orig[t] -> random hmap[orig[t]]) with 255 CUs idle. Confirmed
// -2.7 µs vs 256 threads.
__global__ __launch_bounds__(1024) void bin_kernel(
    const int* __restrict__ orig, const int* __restrict__ hmap,
    int* __restrict__ gidx, int* __restrict__ meta, int ntok)
{
    __shared__ int cnt[E_NUM];
    __shared__ int cur[E_NUM];
    int tid = threadIdx.x;
    if (tid < E_NUM) cnt[tid] = 0;
    __syncthreads();
    for (int t = tid; t < ntok; t += 1024) {
        int b = hmap[orig[t]];
        atomicAdd(&cnt[b], 1);
    }
    __syncthreads();
    if (tid == 0) {
        int off = 0;
        for (int e = 0; e < E_NUM; e++) {
            int ne = cnt[e];
            int nt = (ne + TM - 1) / TM;
            meta[e] = off; meta[8 + e] = ne; meta[16 + e] = nt;
            cur[e] = off;
            off += nt * TM;
        }
        meta[24] = off;
    }
    __syncthreads();
    for (int t = tid; t < ntok; t += 1024) {
        int b = hmap[orig[t]];
        int p = atomicAdd(&cur[b], 1);
        gidx[p] = t;
    }
}

// ---------------------------------------------------------------------------
// 2) Gather x rows -> expert-sorted bf16 buffer; zero padding rows.
// (R10 fused this into gemm1 and regressed 9 µs: fp32 staging doubles bytes,
// scattered rows lose coalescing, +96 VGPR. Keep the separate gather.)
__global__ __launch_bounds__(128) void gather_kernel(
    const float* __restrict__ x, const int* __restrict__ gidx,
    const int* __restrict__ meta, __hip_bfloat16* __restrict__ Xg)
{
    int g = blockIdx.x;
    int e = -1, local = 0;
#pragma unroll
    for (int i = 0; i < E_NUM; i++) {
        int p = meta[i], nt = meta[16 + i];
        if (g >= p && g < p + nt * TM) { e = i; local = g - p; }
    }
    if (e < 0) return;
    int tid = threadIdx.x;
    __hip_bfloat16* orow = Xg + (size_t)g * D_DIM + tid * 4;
    if (local < meta[8 + e]) {
        int t = gidx[g];
        float4 v = ((const float4*)(x + (size_t)t * D_DIM))[tid];
        orow[0] = __float2bfloat16(v.x);
        orow[1] = __float2bfloat16(v.y);
        orow[2] = __float2bfloat16(v.z);
        orow[3] = __float2bfloat16(v.w);
    } else {
        orow[0] = __float2bfloat16(0.f);
        orow[1] = __float2bfloat16(0.f);
        orow[2] = __float2bfloat16(0.f);
        orow[3] = __float2bfloat16(0.f);
    }
}

// ---------------------------------------------------------------------------
// 3) Expert-column MoE GEMM (R9 champion structure, no launch-bounds cap).
// R17: GEMM2 runs split-K=8 -> grid 512 -> 2 blocks/CU. K-slices of W2/Hb are
// disjoint (zero stream duplication, R12's lesson). If natural VGPR <= 256,
// two blocks co-reside and the second fills the first's barrier/vmcnt stalls.
// This is the UNCONFOUNDED occupancy experiment (R15 bundled a VGPR cap that
// likely spilled). GEMM1 untouched.
// A staged via register round-trip (global->VGPR->ds_write): private vmem
// loads are NOT drained by __syncthreads, so A(i+1)/B(i+1) loads issued
// before compute(i) stay in flight across the barrier pair; their vmcnt wait
// lands at the ds_write one full iteration later -> hidden behind compute.
//   A  [CAP, ASTRIDE] bf16 expert-sorted;  W [E][KTOT][WN] fp32 (fused cvt+transpose)
//   RELU: OutBf = bf16(relu(acc + bias));  else OutP[ks][CAP][WN] bf16 partials
// LDS: As [384 x 64k] bf16 48 KB (phys chunk c=(row*8+q): byte c*16 holds
//      src k-bytes (q*16)^((row&7)*16) -> conflict-free b128 reads/writes),
//      Bs [64n x 64k] bf16 8 KB (phys(n,kb)=n*128+(kb^(((n>>2)&7)*16)))
template <int WN, int ASTRIDE, int KTOT, int KS, bool RELU>
__global__ __launch_bounds__(256) void moe_gemm_kernel(
    const __hip_bfloat16* __restrict__ A,
    const float* __restrict__ W,
    const float* __restrict__ bias,
    __hip_bfloat16* __restrict__ OutBf,   // RELU: full output
    __hip_bfloat16* __restrict__ OutP,    // !RELU: bf16 split-K partials
    const int* __restrict__ meta)
{
    constexpr int KLEN = KTOT / KS;           // 512 (GEMM1) / 256 (GEMM2)
    constexpr int NI = KLEN / 64;             // 8 / 4 k-iterations
    constexpr int AJ = MAXRT * 64 * 8 / 256;  // 12 A-chunks (16B) per thread max
    const int e = blockIdx.z;
    const int n0 = blockIdx.x * 64;
    const int ks = blockIdx.y;
    const int kbase = ks * KLEN;

    int nt = meta[16 + e];
    if (nt > MAXRT) nt = MAXRT;
    const int row0 = meta[e];
    const int rows8 = nt * 64 * 8;            // active 16B chunks in A stage

    __shared__ __align__(16) __hip_bfloat16 As[384 * 64];   // 48 KB
    __shared__ __align__(16) __hip_bfloat16 Bs[64 * 64];    // 8 KB

    const int tid = threadIdx.x;
    const int lane = tid & 63, w = tid >> 6;
    const int quad = lane >> 4, l16 = lane & 15;
    const int wr = w >> 1, wc = w & 1;        // 2x2 wave grid per 64x64 tile
    const int kq = tid >> 4;                  // B staging: 4 k-rows
    const int nb = tid & 15;                  // B staging: 4 n-cols

    const __hip_bfloat16* Ab = A + (size_t)row0 * ASTRIDE + kbase;
    const float* Wb = W + ((size_t)e * KTOT + kbase) * WN + n0;

    floatx4 acc[MAXRT][2][2] = {};
    short8 ar[AJ];    // A prefetch registers (48 VGPRs)
    float4 br[4];     // B prefetch registers (16 VGPRs)

#define LOADA(k0) do {                                                        \
    _Pragma("unroll")                                                         \
    for (int j = 0; j < AJ; j++) {                                            \
        int c = tid + j * 256;                                                \
        if (c < rows8) {                                                      \
            int row = c >> 3;                                                 \
            int kk = ((c & 7) * 16) ^ ((row & 7) * 16);   /* bytes */         \
            ar[j] = *(const short8*)(Ab + (size_t)row * ASTRIDE + (k0) + (kk >> 1)); \
        }                                                                     \
    }                                                                         \
} while (0)

#define WRITEA() do {                                                         \
    _Pragma("unroll")                                                         \
    for (int j = 0; j < AJ; j++) {                                            \
        int c = tid + j * 256;                                                \
        if (c < rows8)                                                        \
            *(short8*)((char*)As + c * 16) = ar[j];                           \
    }                                                                         \
} while (0)

#define LOADB(k0) do {                                                        \
    _Pragma("unroll")                                                         \
    for (int r = 0; r < 4; r++)                                               \
        br[r] = *(const float4*)(Wb + (size_t)((k0) + kq * 4 + r) * WN + nb * 4); \
} while (0)

#define WRITEB() do {                                                         \
    _Pragma("unroll")                                                         \
    for (int j = 0; j < 4; j++) {                                             \
        int n = nb * 4 + j;                                                   \
        Pack4 pk;                                                             \
        _Pragma("unroll")                                                     \
        for (int r = 0; r < 4; r++)                                           \
            pk.h[r] = __float2bfloat16(reinterpret_cast<const float*>(&br[r])[j]); \
        *(short4*)((char*)Bs + n * 128 + ((kq * 8) ^ (((n >> 2) & 7) * 16))) = pk.u; \
    }                                                                         \
} while (0)

    LOADA(0);
    LOADB(0);

    for (int i = 0; i < NI; i++) {
        __syncthreads();    // prior iter's LDS reads complete
        WRITEA();           // vmcnt wait for loads issued one iter ago lands here
        WRITEB();
        __syncthreads();
        if (i + 1 < NI) {   // issue next-iter loads; they fly across the barriers
            LOADA((i + 1) * 64);
            LOADB((i + 1) * 64);
        }
#pragma unroll
        for (int kf = 0; kf < 2; kf++) {
            int kb = kf * 64 + quad * 16;
            short8 b[2];
#pragma unroll
            for (int ni = 0; ni < 2; ni++) {
                int n = wc * 32 + ni * 16 + l16;
                b[ni] = *(const short8*)((char*)Bs + n * 128 + (kb ^ (((n >> 2) & 7) * 16)));
            }
#pragma unroll
            for (int rt = 0; rt < MAXRT; rt++) {
                if (rt < nt) {
                    short8 a[2];
#pragma unroll
                    for (int mi = 0; mi < 2; mi++) {
                        int row = rt * 64 + wr * 32 + mi * 16 + l16;
                        a[mi] = *(const short8*)((char*)As + row * 128 + (kb ^ ((row & 7) * 16)));
                    }
#pragma unroll
                    for (int mi = 0; mi < 2; mi++)
#pragma unroll
                        for (int ni = 0; ni < 2; ni++)
                            acc[rt][mi][ni] = __builtin_amdgcn_mfma_f32_16x16x32_bf16(
                                a[mi], b[ni], acc[rt][mi][ni], 0, 0, 0);
                }
            }
        }
    }

    // Epilogue. C/D layout (m89-verified): col = lane&15, row = (lane>>4)*4 + reg
#pragma unroll
    for (int rt = 0; rt < MAXRT; rt++) {
        if (rt >= nt) break;
#pragma unroll
        for (int ni = 0; ni < 2; ni++) {
            int col = n0 + wc * 32 + ni * 16 + l16;
            float bv = RELU ? bias[e * WN + col] : 0.f;
#pragma unroll
            for (int mi = 0; mi < 2; mi++) {
#pragma unroll
                for (int r = 0; r < 4; r++) {
                    int grow = row0 + rt * 64 + wr * 32 + mi * 16 + quad * 4 + r;
                    float v = acc[rt][mi][ni][r] + bv;
                    if constexpr (RELU) {
                        v = v > 0.f ? v : 0.f;
                        OutBf[(size_t)grow * WN + col] = __float2bfloat16(v);
                    } else {
                        OutP[((size_t)ks * CAP + grow) * WN + col] = __float2bfloat16(v);
                    }
                }
            }
        }
    }
#undef LOADA
#undef WRITEA
#undef LOADB
#undef WRITEB
}

// ---------------------------------------------------------------------------
// 4) Residual + b2 + 8-way bf16 split-K sum + LayerNorm, scatter to token order.
__global__ __launch_bounds__(128) void ln_kernel(
    const float* __restrict__ x, const __hip_bfloat16* __restrict__ Yp,
    const float* __restrict__ b2,
    const float* __restrict__ gamma, const float* __restrict__ beta,
    const int* __restrict__ gidx, const int* __restrict__ meta,
    float* __restrict__ out)
{
    int g = blockIdx.x;
    int e = -1;
#pragma unroll
    for (int i = 0; i < E_NUM; i++) {
        int p = meta[i], ne = meta[8 + i];
        if (g >= p && g - p < ne) e = i;
    }
    if (e < 0) return;   // padding row or beyond total
    int t = gidx[g];
    int tid = threadIdx.x;

    float4 xv = ((const float4*)(x + (size_t)t * D_DIM))[tid];
    float4 bb = ((const float4*)(b2 + (size_t)e * D_DIM))[tid];
    float z0 = xv.x + bb.x, z1 = xv.y + bb.y, z2 = xv.z + bb.z, z3 = xv.w + bb.w;
#pragma unroll
    for (int s4 = 0; s4 < 8; s4++) {
        union { short4 u; __hip_bfloat16 h[4]; } yv;
        yv.u = ((const short4*)(Yp + (size_t)(s4 * CAP + g) * D_DIM))[tid];
        z0 += __bfloat162float(yv.h[0]);
        z1 += __bfloat162float(yv.h[1]);
        z2 += __bfloat162float(yv.h[2]);
        z3 += __bfloat162float(yv.h[3]);
    }

    float s = z0 + z1 + z2 + z3;
    float ss = z0 * z0 + z1 * z1 + z2 * z2 + z3 * z3;
#pragma unroll
    for (int off = 32; off > 0; off >>= 1) {
        s  += __shfl_down(s, off, 64);
        ss += __shfl_down(ss, off, 64);
    }
    __shared__ float red[4];
    int lane = tid & 63, wv = tid >> 6;
    if (lane == 0) { red[wv] = s; red[2 + wv] = ss; }
    __syncthreads();
    float S = red[0] + red[1];
    float SS = red[2] + red[3];
    float mu = S * (1.f / D_DIM);
    float var = SS * (1.f / D_DIM) - mu * mu;
    float inv = rsqrtf(var + 1e-5f);

    float4 gv = ((const float4*)gamma)[tid];
    float4 bv = ((const float4*)beta)[tid];
    float4 o;
    o.x = (z0 - mu) * inv * gv.x + bv.x;
    o.y = (z1 - mu) * inv * gv.y + bv.y;
    o.z = (z2 - mu) * inv * gv.z + bv.z;
    o.w = (z3 - mu) * inv * gv.w + bv.w;
    ((float4*)(out + (size_t)t * D_DIM))[tid] = o;
}

// ---------------------------------------------------------------------------
extern "C" void kernel_launch(void* const* d_in, const int* in_sizes, int n_in,
                              void* d_out, int out_size, void* d_ws, size_t ws_size,
                              hipStream_t stream)
{
    const float* x     = (const float*)d_in[0];
    const float* W1    = (const float*)d_in[1];
    const float* b1    = (const float*)d_in[2];
    const float* W2    = (const float*)d_in[3];
    const float* b2    = (const float*)d_in[4];
    const float* gamma = (const float*)d_in[5];
    const float* beta  = (const float*)d_in[6];
    const int* orig    = (const int*)d_in[7];
    const int* hmap    = (const int*)d_in[8];
    float* out = (float*)d_out;
    int ntok = in_sizes[7];   // B*S = 2048

    // Workspace layout (~34.1 MB)
    char* ws = (char*)d_ws;
    __hip_bfloat16* Yp  = (__hip_bfloat16*)(ws);             // [8][CAP][512] bf16, 20.97 MB
    __hip_bfloat16* Hb  = (__hip_bfloat16*)(ws + 20971520);  // [CAP][2048] bf16, 10.49 MB
    __hip_bfloat16* Xg  = (__hip_bfloat16*)(ws + 31457280);  // [CAP][512] bf16, 2.62 MB
    int*            gidx= (int*)(ws + 34078720);             // [CAP]
    int*            meta= (int*)(ws + 34088960);             // 32 ints

    hipLaunchKernelGGL(bin_kernel, dim3(1), dim3(1024), 0, stream,
                       orig, hmap, gidx, meta, ntok);
    hipLaunchKernelGGL(gather_kernel, dim3(CAP), dim3(128), 0, stream,
                       x, gidx, meta, Xg);
    // GEMM1: Xg[rows,512] x W1[E][512][2048] -> relu(+b1) -> bf16 Hb. grid 256.
    hipLaunchKernelGGL((moe_gemm_kernel<H_DIM, D_DIM, D_DIM, 1, true>),
                       dim3(H_DIM / 64, 1, E_NUM), dim3(256), 0, stream,
                       Xg, W1, b1, Hb, (__hip_bfloat16*)nullptr, meta);
    // GEMM2: Hb[rows,2048] x W2[E][2048][512] -> bf16 partials (split-K=8).
    // grid (8 n, 8 ks, 8 e) = 512 blocks -> 2 blocks/CU. K-slices disjoint:
    // zero stream duplication. No VGPR cap (R15's confound removed).
    hipLaunchKernelGGL((moe_gemm_kernel<D_DIM, H_DIM, H_DIM, 8, false>),
                       dim3(D_DIM / 64, 8, E_NUM), dim3(256), 0, stream,
                       Hb, W2, (const float*)nullptr, (__hip_bfloat16*)nullptr, Yp, meta);
    hipLaunchKernelGGL(ln_kernel, dim3(CAP), dim3(128), 0, stream,
                       x, Yp, b2, gamma, beta, gidx, meta, out);
}

// Round 10
// 144.463 us; speedup vs baseline: 1.1776x; 1.0332x over previous
//
#include <hip/hip_runtime.h>
#include <hip/hip_bf16.h>
#include <stdint.h>

// Problem constants (fixed by reference): B=4,S=512 -> 2048 tokens, D=512, H=2048, E=8
#define D_DIM 512
#define H_DIM 2048
#define E_NUM 8
#define TM 64            // row-tile (padding granularity)
#define CAP 2560         // 2048 tokens + worst-case per-expert padding
#define MAXRT 6          // max row-tiles per expert (384 rows; ne~256±15, 8.5 sigma)

typedef __attribute__((ext_vector_type(8))) short short8;
typedef __attribute__((ext_vector_type(4))) float floatx4;

union Pack4 { short4 u; __hip_bfloat16 h[4]; };

// ---------------------------------------------------------------------------
// 1) Token binning. meta[0..7]=padded offset, [8..15]=ne, [16..23]=ntiles, [24]=total
// R16: 1024 threads. bin is 1 block; its two passes are chains of dependent
// global loads (orig[t] -> random hmap[orig[t]]) with 255 CUs idle. Confirmed
// -2.7 µs vs 256 threads.
__global__ __launch_bounds__(1024) void bin_kernel(
    const int* __restrict__ orig, const int* __restrict__ hmap,
    int* __restrict__ gidx, int* __restrict__ meta, int ntok)
{
    __shared__ int cnt[E_NUM];
    __shared__ int cur[E_NUM];
    int tid = threadIdx.x;
    if (tid < E_NUM) cnt[tid] = 0;
    __syncthreads();
    for (int t = tid; t < ntok; t += 1024) {
        int b = hmap[orig[t]];
        atomicAdd(&cnt[b], 1);
    }
    __syncthreads();
    if (tid == 0) {
        int off = 0;
        for (int e = 0; e < E_NUM; e++) {
            int ne = cnt[e];
            int nt = (ne + TM - 1) / TM;
            meta[e] = off; meta[8 + e] = ne; meta[16 + e] = nt;
            cur[e] = off;
            off += nt * TM;
        }
        meta[24] = off;
    }
    __syncthreads();
    for (int t = tid; t < ntok; t += 1024) {
        int b = hmap[orig[t]];
        int p = atomicAdd(&cur[b], 1);
        gidx[p] = t;
    }
}

// ---------------------------------------------------------------------------
// 2) Gather x rows -> expert-sorted bf16 buffer; zero padding rows.
// (R10 fused this into gemm1 and regressed 9 µs: fp32 staging doubles bytes,
// scattered rows lose coalescing, +96 VGPR. Keep the separate gather.)
__global__ __launch_bounds__(128) void gather_kernel(
    const float* __restrict__ x, const int* __restrict__ gidx,
    const int* __restrict__ meta, __hip_bfloat16* __restrict__ Xg)
{
    int g = blockIdx.x;
    int e = -1, local = 0;
#pragma unroll
    for (int i = 0; i < E_NUM; i++) {
        int p = meta[i], nt = meta[16 + i];
        if (g >= p && g < p + nt * TM) { e = i; local = g - p; }
    }
    if (e < 0) return;
    int tid = threadIdx.x;
    __hip_bfloat16* orow = Xg + (size_t)g * D_DIM + tid * 4;
    if (local < meta[8 + e]) {
        int t = gidx[g];
        float4 v = ((const float4*)(x + (size_t)t * D_DIM))[tid];
        orow[0] = __float2bfloat16(v.x);
        orow[1] = __float2bfloat16(v.y);
        orow[2] = __float2bfloat16(v.z);
        orow[3] = __float2bfloat16(v.w);
    } else {
        orow[0] = __float2bfloat16(0.f);
        orow[1] = __float2bfloat16(0.f);
        orow[2] = __float2bfloat16(0.f);
        orow[3] = __float2bfloat16(0.f);
    }
}

// ---------------------------------------------------------------------------
// 3) Expert-column MoE GEMM (R9 champion pipeline; R17 KS=8; R18 grid order).
// R18: GEMM2 grid reordered to (x=ks, y=n, z=e). With x=n (old), the 8
// n-blocks sharing one Hb A-slice had id%8 = n -> 8 DIFFERENT XCDs, each
// fetching the slice from L3 separately: 8x10.5 = 84 MB of L3 reads. With
// x=ks, id%8 = ks -> the 8 sharers are co-resident on ONE XCD, concurrently
// on 8 of its CUs: slice lands in that XCD's L2 once (1.3 MB/XCD working
// set < 4 MB). Hb traffic 84 -> 10.5 MB. W2 k-slices disjoint, unchanged.
// Compile-time axis select via (KS>1); GEMM1 (KS=1) untouched.
// A staged via register round-trip (global->VGPR->ds_write): private vmem
// loads are NOT drained by __syncthreads, so A(i+1)/B(i+1) loads issued
// before compute(i) stay in flight across the barrier pair; their vmcnt wait
// lands at the ds_write one full iteration later -> hidden behind compute.
//   A  [CAP, ASTRIDE] bf16 expert-sorted;  W [E][KTOT][WN] fp32 (fused cvt+transpose)
//   RELU: OutBf = bf16(relu(acc + bias));  else OutP[ks][CAP][WN] bf16 partials
// LDS: As [384 x 64k] bf16 48 KB (phys chunk c=(row*8+q): byte c*16 holds
//      src k-bytes (q*16)^((row&7)*16) -> conflict-free b128 reads/writes),
//      Bs [64n x 64k] bf16 8 KB (phys(n,kb)=n*128+(kb^(((n>>2)&7)*16)))
template <int WN, int ASTRIDE, int KTOT, int KS, bool RELU>
__global__ __launch_bounds__(256) void moe_gemm_kernel(
    const __hip_bfloat16* __restrict__ A,
    const float* __restrict__ W,
    const float* __restrict__ bias,
    __hip_bfloat16* __restrict__ OutBf,   // RELU: full output
    __hip_bfloat16* __restrict__ OutP,    // !RELU: bf16 split-K partials
    const int* __restrict__ meta)
{
    constexpr int KLEN = KTOT / KS;           // 512 (GEMM1) / 256 (GEMM2)
    constexpr int NI = KLEN / 64;             // 8 / 4 k-iterations
    constexpr int AJ = MAXRT * 64 * 8 / 256;  // 12 A-chunks (16B) per thread max
    const int e = blockIdx.z;
    const int n0 = (KS > 1 ? blockIdx.y : blockIdx.x) * 64;   // R18 axis select
    const int ks = (KS > 1 ? blockIdx.x : blockIdx.y);
    const int kbase = ks * KLEN;

    int nt = meta[16 + e];
    if (nt > MAXRT) nt = MAXRT;
    const int row0 = meta[e];
    const int rows8 = nt * 64 * 8;            // active 16B chunks in A stage

    __shared__ __align__(16) __hip_bfloat16 As[384 * 64];   // 48 KB
    __shared__ __align__(16) __hip_bfloat16 Bs[64 * 64];    // 8 KB

    const int tid = threadIdx.x;
    const int lane = tid & 63, w = tid >> 6;
    const int quad = lane >> 4, l16 = lane & 15;
    const int wr = w >> 1, wc = w & 1;        // 2x2 wave grid per 64x64 tile
    const int kq = tid >> 4;                  // B staging: 4 k-rows
    const int nb = tid & 15;                  // B staging: 4 n-cols

    const __hip_bfloat16* Ab = A + (size_t)row0 * ASTRIDE + kbase;
    const float* Wb = W + ((size_t)e * KTOT + kbase) * WN + n0;

    floatx4 acc[MAXRT][2][2] = {};
    short8 ar[AJ];    // A prefetch registers (48 VGPRs)
    float4 br[4];     // B prefetch registers (16 VGPRs)

#define LOADA(k0) do {                                                        \
    _Pragma("unroll")                                                         \
    for (int j = 0; j < AJ; j++) {                                            \
        int c = tid + j * 256;                                                \
        if (c < rows8) {                                                      \
            int row = c >> 3;                                                 \
            int kk = ((c & 7) * 16) ^ ((row & 7) * 16);   /* bytes */         \
            ar[j] = *(const short8*)(Ab + (size_t)row * ASTRIDE + (k0) + (kk >> 1)); \
        }                                                                     \
    }                                                                         \
} while (0)

#define WRITEA() do {                                                         \
    _Pragma("unroll")                                                         \
    for (int j = 0; j < AJ; j++) {                                            \
        int c = tid + j * 256;                                                \
        if (c < rows8)                                                        \
            *(short8*)((char*)As + c * 16) = ar[j];                           \
    }                                                                         \
} while (0)

#define LOADB(k0) do {                                                        \
    _Pragma("unroll")                                                         \
    for (int r = 0; r < 4; r++)                                               \
        br[r] = *(const float4*)(Wb + (size_t)((k0) + kq * 4 + r) * WN + nb * 4); \
} while (0)

#define WRITEB() do {                                                         \
    _Pragma("unroll")                                                         \
    for (int j = 0; j < 4; j++) {                                             \
        int n = nb * 4 + j;                                                   \
        Pack4 pk;                                                             \
        _Pragma("unroll")                                                     \
        for (int r = 0; r < 4; r++)                                           \
            pk.h[r] = __float2bfloat16(reinterpret_cast<const float*>(&br[r])[j]); \
        *(short4*)((char*)Bs + n * 128 + ((kq * 8) ^ (((n >> 2) & 7) * 16))) = pk.u; \
    }                                                                         \
} while (0)

    LOADA(0);
    LOADB(0);

    for (int i = 0; i < NI; i++) {
        __syncthreads();    // prior iter's LDS reads complete
        WRITEA();           // vmcnt wait for loads issued one iter ago lands here
        WRITEB();
        __syncthreads();
        if (i + 1 < NI) {   // issue next-iter loads; they fly across the barriers
            LOADA((i + 1) * 64);
            LOADB((i + 1) * 64);
        }
#pragma unroll
        for (int kf = 0; kf < 2; kf++) {
            int kb = kf * 64 + quad * 16;
            short8 b[2];
#pragma unroll
            for (int ni = 0; ni < 2; ni++) {
                int n = wc * 32 + ni * 16 + l16;
                b[ni] = *(const short8*)((char*)Bs + n * 128 + (kb ^ (((n >> 2) & 7) * 16)));
            }
#pragma unroll
            for (int rt = 0; rt < MAXRT; rt++) {
                if (rt < nt) {
                    short8 a[2];
#pragma unroll
                    for (int mi = 0; mi < 2; mi++) {
                        int row = rt * 64 + wr * 32 + mi * 16 + l16;
                        a[mi] = *(const short8*)((char*)As + row * 128 + (kb ^ ((row & 7) * 16)));
                    }
#pragma unroll
                    for (int mi = 0; mi < 2; mi++)
#pragma unroll
                        for (int ni = 0; ni < 2; ni++)
                            acc[rt][mi][ni] = __builtin_amdgcn_mfma_f32_16x16x32_bf16(
                                a[mi], b[ni], acc[rt][mi][ni], 0, 0, 0);
                }
            }
        }
    }

    // Epilogue. C/D layout (m89-verified): col = lane&15, row = (lane>>4)*4 + reg
#pragma unroll
    for (int rt = 0; rt < MAXRT; rt++) {
        if (rt >= nt) break;
#pragma unroll
        for (int ni = 0; ni < 2; ni++) {
            int col = n0 + wc * 32 + ni * 16 + l16;
            float bv = RELU ? bias[e * WN + col] : 0.f;
#pragma unroll
            for (int mi = 0; mi < 2; mi++) {
#pragma unroll
                for (int r = 0; r < 4; r++) {
                    int grow = row0 + rt * 64 + wr * 32 + mi * 16 + quad * 4 + r;
                    float v = acc[rt][mi][ni][r] + bv;
                    if constexpr (RELU) {
                        v = v > 0.f ? v : 0.f;
                        OutBf[(size_t)grow * WN + col] = __float2bfloat16(v);
                    } else {
                        OutP[((size_t)ks * CAP + grow) * WN + col] = __float2bfloat16(v);
                    }
                }
            }
        }
    }
#undef LOADA
#undef WRITEA
#undef LOADB
#undef WRITEB
}

// ---------------------------------------------------------------------------
// 4) Residual + b2 + 8-way bf16 split-K sum + LayerNorm, scatter to token order.
__global__ __launch_bounds__(128) void ln_kernel(
    const float* __restrict__ x, const __hip_bfloat16* __restrict__ Yp,
    const float* __restrict__ b2,
    const float* __restrict__ gamma, const float* __restrict__ beta,
    const int* __restrict__ gidx, const int* __restrict__ meta,
    float* __restrict__ out)
{
    int g = blockIdx.x;
    int e = -1;
#pragma unroll
    for (int i = 0; i < E_NUM; i++) {
        int p = meta[i], ne = meta[8 + i];
        if (g >= p && g - p < ne) e = i;
    }
    if (e < 0) return;   // padding row or beyond total
    int t = gidx[g];
    int tid = threadIdx.x;

    float4 xv = ((const float4*)(x + (size_t)t * D_DIM))[tid];
    float4 bb = ((const float4*)(b2 + (size_t)e * D_DIM))[tid];
    float z0 = xv.x + bb.x, z1 = xv.y + bb.y, z2 = xv.z + bb.z, z3 = xv.w + bb.w;
#pragma unroll
    for (int s4 = 0; s4 < 8; s4++) {
        union { short4 u; __hip_bfloat16 h[4]; } yv;
        yv.u = ((const short4*)(Yp + (size_t)(s4 * CAP + g) * D_DIM))[tid];
        z0 += __bfloat162float(yv.h[0]);
        z1 += __bfloat162float(yv.h[1]);
        z2 += __bfloat162float(yv.h[2]);
        z3 += __bfloat162float(yv.h[3]);
    }

    float s = z0 + z1 + z2 + z3;
    float ss = z0 * z0 + z1 * z1 + z2 * z2 + z3 * z3;
#pragma unroll
    for (int off = 32; off > 0; off >>= 1) {
        s  += __shfl_down(s, off, 64);
        ss += __shfl_down(ss, off, 64);
    }
    __shared__ float red[4];
    int lane = tid & 63, wv = tid >> 6;
    if (lane == 0) { red[wv] = s; red[2 + wv] = ss; }
    __syncthreads();
    float S = red[0] + red[1];
    float SS = red[2] + red[3];
    float mu = S * (1.f / D_DIM);
    float var = SS * (1.f / D_DIM) - mu * mu;
    float inv = rsqrtf(var + 1e-5f);

    float4 gv = ((const float4*)gamma)[tid];
    float4 bv = ((const float4*)beta)[tid];
    float4 o;
    o.x = (z0 - mu) * inv * gv.x + bv.x;
    o.y = (z1 - mu) * inv * gv.y + bv.y;
    o.z = (z2 - mu) * inv * gv.z + bv.z;
    o.w = (z3 - mu) * inv * gv.w + bv.w;
    ((float4*)(out + (size_t)t * D_DIM))[tid] = o;
}

// ---------------------------------------------------------------------------
extern "C" void kernel_launch(void* const* d_in, const int* in_sizes, int n_in,
                              void* d_out, int out_size, void* d_ws, size_t ws_size,
                              hipStream_t stream)
{
    const float* x     = (const float*)d_in[0];
    const float* W1    = (const float*)d_in[1];
    const float* b1    = (const float*)d_in[2];
    const float* W2    = (const float*)d_in[3];
    const float* b2    = (const float*)d_in[4];
    const float* gamma = (const float*)d_in[5];
    const float* beta  = (const float*)d_in[6];
    const int* orig    = (const int*)d_in[7];
    const int* hmap    = (const int*)d_in[8];
    float* out = (float*)d_out;
    int ntok = in_sizes[7];   // B*S = 2048

    // Workspace layout (~34.1 MB)
    char* ws = (char*)d_ws;
    __hip_bfloat16* Yp  = (__hip_bfloat16*)(ws);             // [8][CAP][512] bf16, 20.97 MB
    __hip_bfloat16* Hb  = (__hip_bfloat16*)(ws + 20971520);  // [CAP][2048] bf16, 10.49 MB
    __hip_bfloat16* Xg  = (__hip_bfloat16*)(ws + 31457280);  // [CAP][512] bf16, 2.62 MB
    int*            gidx= (int*)(ws + 34078720);             // [CAP]
    int*            meta= (int*)(ws + 34088960);             // 32 ints

    hipLaunchKernelGGL(bin_kernel, dim3(1), dim3(1024), 0, stream,
                       orig, hmap, gidx, meta, ntok);
    hipLaunchKernelGGL(gather_kernel, dim3(CAP), dim3(128), 0, stream,
                       x, gidx, meta, Xg);
    // GEMM1: Xg[rows,512] x W1[E][512][2048] -> relu(+b1) -> bf16 Hb. grid 256.
    hipLaunchKernelGGL((moe_gemm_kernel<H_DIM, D_DIM, D_DIM, 1, true>),
                       dim3(H_DIM / 64, 1, E_NUM), dim3(256), 0, stream,
                       Xg, W1, b1, Hb, (__hip_bfloat16*)nullptr, meta);
    // GEMM2: Hb[rows,2048] x W2[E][2048][512] -> bf16 partials (split-K=8).
    // R18 grid (8 ks, 8 n, 8 e): id%8 = ks -> the 8 n-blocks sharing an Hb
    // slice are co-XCD; slice cached once in that XCD's L2.
    hipLaunchKernelGGL((moe_gemm_kernel<D_DIM, H_DIM, H_DIM, 8, false>),
                       dim3(8, D_DIM / 64, E_NUM), dim3(256), 0, stream,
                       Hb, W2, (const float*)nullptr, (__hip_bfloat16*)nullptr, Yp, meta);
    hipLaunchKernelGGL(ln_kernel, dim3(CAP), dim3(128), 0, stream,
                       x, Yp, b2, gamma, beta, gidx, meta, out);
}

// Round 11
// 143.062 us; speedup vs baseline: 1.1892x; 1.0098x over previous
//
#include <hip/hip_runtime.h>
#include <hip/hip_bf16.h>
#include <stdint.h>

// Problem constants (fixed by reference): B=4,S=512 -> 2048 tokens, D=512, H=2048, E=8
#define D_DIM 512
#define H_DIM 2048
#define E_NUM 8
#define TM 64            // row-tile (padding granularity)
#define CAP 2560         // 2048 tokens + worst-case per-expert padding
#define MAXRT 6          // max row-tiles per expert (384 rows; ne~256±15, 8.5 sigma)

typedef __attribute__((ext_vector_type(8))) short short8;
typedef __attribute__((ext_vector_type(4))) float floatx4;

union Pack4 { short4 u; __hip_bfloat16 h[4]; };

// ---------------------------------------------------------------------------
// 1) Token binning. meta[0..7]=padded offset, [8..15]=ne, [16..23]=ntiles, [24]=total
// R16: 1024 threads. bin is 1 block; its two passes are chains of dependent
// global loads (orig[t] -> random hmap[orig[t]]) with 255 CUs idle. Confirmed
// -2.7 µs vs 256 threads.
__global__ __launch_bounds__(1024) void bin_kernel(
    const int* __restrict__ orig, const int* __restrict__ hmap,
    int* __restrict__ gidx, int* __restrict__ meta, int ntok)
{
    __shared__ int cnt[E_NUM];
    __shared__ int cur[E_NUM];
    int tid = threadIdx.x;
    if (tid < E_NUM) cnt[tid] = 0;
    __syncthreads();
    for (int t = tid; t < ntok; t += 1024) {
        int b = hmap[orig[t]];
        atomicAdd(&cnt[b], 1);
    }
    __syncthreads();
    if (tid == 0) {
        int off = 0;
        for (int e = 0; e < E_NUM; e++) {
            int ne = cnt[e];
            int nt = (ne + TM - 1) / TM;
            meta[e] = off; meta[8 + e] = ne; meta[16 + e] = nt;
            cur[e] = off;
            off += nt * TM;
        }
        meta[24] = off;
    }
    __syncthreads();
    for (int t = tid; t < ntok; t += 1024) {
        int b = hmap[orig[t]];
        int p = atomicAdd(&cur[b], 1);
        gidx[p] = t;
    }
}

// ---------------------------------------------------------------------------
// 2) Gather x rows -> expert-sorted bf16 buffer; zero padding rows.
// (R10 fused this into gemm1 and regressed 9 µs: fp32 staging doubles bytes,
// scattered rows lose coalescing, +96 VGPR. Keep the separate gather.)
__global__ __launch_bounds__(128) void gather_kernel(
    const float* __restrict__ x, const int* __restrict__ gidx,
    const int* __restrict__ meta, __hip_bfloat16* __restrict__ Xg)
{
    int g = blockIdx.x;
    int e = -1, local = 0;
#pragma unroll
    for (int i = 0; i < E_NUM; i++) {
        int p = meta[i], nt = meta[16 + i];
        if (g >= p && g < p + nt * TM) { e = i; local = g - p; }
    }
    if (e < 0) return;
    int tid = threadIdx.x;
    __hip_bfloat16* orow = Xg + (size_t)g * D_DIM + tid * 4;
    if (local < meta[8 + e]) {
        int t = gidx[g];
        float4 v = ((const float4*)(x + (size_t)t * D_DIM))[tid];
        orow[0] = __float2bfloat16(v.x);
        orow[1] = __float2bfloat16(v.y);
        orow[2] = __float2bfloat16(v.z);
        orow[3] = __float2bfloat16(v.w);
    } else {
        orow[0] = __float2bfloat16(0.f);
        orow[1] = __float2bfloat16(0.f);
        orow[2] = __float2bfloat16(0.f);
        orow[3] = __float2bfloat16(0.f);
    }
}

// ---------------------------------------------------------------------------
// 3) Expert-column MoE GEMM (R9 pipeline; R17 KS=8; R18/R19 XCD grid maps).
// XCD mechanism (confirmed R18, -4.8 µs): blocks land on XCD (linear id % 8);
// co-locating all blocks that share an A-slice onto ONE XCD makes the slice a
// one-time L2 fill instead of 8 separate L3 fetches.
//   R18 GEMM2: grid (x=ks, y=n, z=e) -> id%8 = ks; the 8 n-blocks sharing an
//     Hb k-slice are co-XCD. Hb L3 traffic 84 -> 10.5 MB.
//   R19 GEMM1: grid (x=e, y=1, z=n) -> id%8 = e; the 32 n-blocks sharing an
//     expert's Xg slice are co-XCD (slice ~384 KB << 4 MB L2). Xg L3 traffic
//     ~21 -> 2.6 MB. (R11b tried this confounded with a wave-tiling change;
//     this is the clean test.) W n-slices disjoint per block either way.
// A staged via register round-trip (global->VGPR->ds_write): private vmem
// loads are NOT drained by __syncthreads, so A(i+1)/B(i+1) loads issued
// before compute(i) stay in flight across the barrier pair; their vmcnt wait
// lands at the ds_write one full iteration later -> hidden behind compute.
//   A  [CAP, ASTRIDE] bf16 expert-sorted;  W [E][KTOT][WN] fp32 (fused cvt+transpose)
//   RELU: OutBf = bf16(relu(acc + bias));  else OutP[ks][CAP][WN] bf16 partials
// LDS: As [384 x 64k] bf16 48 KB (phys chunk c=(row*8+q): byte c*16 holds
//      src k-bytes (q*16)^((row&7)*16) -> conflict-free b128 reads/writes),
//      Bs [64n x 64k] bf16 8 KB (phys(n,kb)=n*128+(kb^(((n>>2)&7)*16)))
template <int WN, int ASTRIDE, int KTOT, int KS, bool RELU>
__global__ __launch_bounds__(256) void moe_gemm_kernel(
    const __hip_bfloat16* __restrict__ A,
    const float* __restrict__ W,
    const float* __restrict__ bias,
    __hip_bfloat16* __restrict__ OutBf,   // RELU: full output
    __hip_bfloat16* __restrict__ OutP,    // !RELU: bf16 split-K partials
    const int* __restrict__ meta)
{
    constexpr int KLEN = KTOT / KS;           // 512 (GEMM1) / 256 (GEMM2)
    constexpr int NI = KLEN / 64;             // 8 / 4 k-iterations
    constexpr int AJ = MAXRT * 64 * 8 / 256;  // 12 A-chunks (16B) per thread max
    // Axis select: KS>1 (GEMM2): (x=ks, y=n, z=e). KS==1 (GEMM1): (x=e, z=n).
    const int e  = (KS > 1) ? blockIdx.z : blockIdx.x;
    const int n0 = ((KS > 1) ? blockIdx.y : blockIdx.z) * 64;
    const int ks = (KS > 1) ? blockIdx.x : 0;
    const int kbase = ks * KLEN;

    int nt = meta[16 + e];
    if (nt > MAXRT) nt = MAXRT;
    const int row0 = meta[e];
    const int rows8 = nt * 64 * 8;            // active 16B chunks in A stage

    __shared__ __align__(16) __hip_bfloat16 As[384 * 64];   // 48 KB
    __shared__ __align__(16) __hip_bfloat16 Bs[64 * 64];    // 8 KB

    const int tid = threadIdx.x;
    const int lane = tid & 63, w = tid >> 6;
    const int quad = lane >> 4, l16 = lane & 15;
    const int wr = w >> 1, wc = w & 1;        // 2x2 wave grid per 64x64 tile
    const int kq = tid >> 4;                  // B staging: 4 k-rows
    const int nb = tid & 15;                  // B staging: 4 n-cols

    const __hip_bfloat16* Ab = A + (size_t)row0 * ASTRIDE + kbase;
    const float* Wb = W + ((size_t)e * KTOT + kbase) * WN + n0;

    floatx4 acc[MAXRT][2][2] = {};
    short8 ar[AJ];    // A prefetch registers (48 VGPRs)
    float4 br[4];     // B prefetch registers (16 VGPRs)

#define LOADA(k0) do {                                                        \
    _Pragma("unroll")                                                         \
    for (int j = 0; j < AJ; j++) {                                            \
        int c = tid + j * 256;                                                \
        if (c < rows8) {                                                      \
            int row = c >> 3;                                                 \
            int kk = ((c & 7) * 16) ^ ((row & 7) * 16);   /* bytes */         \
            ar[j] = *(const short8*)(Ab + (size_t)row * ASTRIDE + (k0) + (kk >> 1)); \
        }                                                                     \
    }                                                                         \
} while (0)

#define WRITEA() do {                                                         \
    _Pragma("unroll")                                                         \
    for (int j = 0; j < AJ; j++) {                                            \
        int c = tid + j * 256;                                                \
        if (c < rows8)                                                        \
            *(short8*)((char*)As + c * 16) = ar[j];                           \
    }                                                                         \
} while (0)

#define LOADB(k0) do {                                                        \
    _Pragma("unroll")                                                         \
    for (int r = 0; r < 4; r++)                                               \
        br[r] = *(const float4*)(Wb + (size_t)((k0) + kq * 4 + r) * WN + nb * 4); \
} while (0)

#define WRITEB() do {                                                         \
    _Pragma("unroll")                                                         \
    for (int j = 0; j < 4; j++) {                                             \
        int n = nb * 4 + j;                                                   \
        Pack4 pk;                                                             \
        _Pragma("unroll")                                                     \
        for (int r = 0; r < 4; r++)                                           \
            pk.h[r] = __float2bfloat16(reinterpret_cast<const float*>(&br[r])[j]); \
        *(short4*)((char*)Bs + n * 128 + ((kq * 8) ^ (((n >> 2) & 7) * 16))) = pk.u; \
    }                                                                         \
} while (0)

    LOADA(0);
    LOADB(0);

    for (int i = 0; i < NI; i++) {
        __syncthreads();    // prior iter's LDS reads complete
        WRITEA();           // vmcnt wait for loads issued one iter ago lands here
        WRITEB();
        __syncthreads();
        if (i + 1 < NI) {   // issue next-iter loads; they fly across the barriers
            LOADA((i + 1) * 64);
            LOADB((i + 1) * 64);
        }
#pragma unroll
        for (int kf = 0; kf < 2; kf++) {
            int kb = kf * 64 + quad * 16;
            short8 b[2];
#pragma unroll
            for (int ni = 0; ni < 2; ni++) {
                int n = wc * 32 + ni * 16 + l16;
                b[ni] = *(const short8*)((char*)Bs + n * 128 + (kb ^ (((n >> 2) & 7) * 16)));
            }
#pragma unroll
            for (int rt = 0; rt < MAXRT; rt++) {
                if (rt < nt) {
                    short8 a[2];
#pragma unroll
                    for (int mi = 0; mi < 2; mi++) {
                        int row = rt * 64 + wr * 32 + mi * 16 + l16;
                        a[mi] = *(const short8*)((char*)As + row * 128 + (kb ^ ((row & 7) * 16)));
                    }
#pragma unroll
                    for (int mi = 0; mi < 2; mi++)
#pragma unroll
                        for (int ni = 0; ni < 2; ni++)
                            acc[rt][mi][ni] = __builtin_amdgcn_mfma_f32_16x16x32_bf16(
                                a[mi], b[ni], acc[rt][mi][ni], 0, 0, 0);
                }
            }
        }
    }

    // Epilogue. C/D layout (m89-verified): col = lane&15, row = (lane>>4)*4 + reg
#pragma unroll
    for (int rt = 0; rt < MAXRT; rt++) {
        if (rt >= nt) break;
#pragma unroll
        for (int ni = 0; ni < 2; ni++) {
            int col = n0 + wc * 32 + ni * 16 + l16;
            float bv = RELU ? bias[e * WN + col] : 0.f;
#pragma unroll
            for (int mi = 0; mi < 2; mi++) {
#pragma unroll
                for (int r = 0; r < 4; r++) {
                    int grow = row0 + rt * 64 + wr * 32 + mi * 16 + quad * 4 + r;
                    float v = acc[rt][mi][ni][r] + bv;
                    if constexpr (RELU) {
                        v = v > 0.f ? v : 0.f;
                        OutBf[(size_t)grow * WN + col] = __float2bfloat16(v);
                    } else {
                        OutP[((size_t)ks * CAP + grow) * WN + col] = __float2bfloat16(v);
                    }
                }
            }
        }
    }
#undef LOADA
#undef WRITEA
#undef LOADB
#undef WRITEB
}

// ---------------------------------------------------------------------------
// 4) Residual + b2 + 8-way bf16 split-K sum + LayerNorm, scatter to token order.
__global__ __launch_bounds__(128) void ln_kernel(
    const float* __restrict__ x, const __hip_bfloat16* __restrict__ Yp,
    const float* __restrict__ b2,
    const float* __restrict__ gamma, const float* __restrict__ beta,
    const int* __restrict__ gidx, const int* __restrict__ meta,
    float* __restrict__ out)
{
    int g = blockIdx.x;
    int e = -1;
#pragma unroll
    for (int i = 0; i < E_NUM; i++) {
        int p = meta[i], ne = meta[8 + i];
        if (g >= p && g - p < ne) e = i;
    }
    if (e < 0) return;   // padding row or beyond total
    int t = gidx[g];
    int tid = threadIdx.x;

    float4 xv = ((const float4*)(x + (size_t)t * D_DIM))[tid];
    float4 bb = ((const float4*)(b2 + (size_t)e * D_DIM))[tid];
    float z0 = xv.x + bb.x, z1 = xv.y + bb.y, z2 = xv.z + bb.z, z3 = xv.w + bb.w;
#pragma unroll
    for (int s4 = 0; s4 < 8; s4++) {
        union { short4 u; __hip_bfloat16 h[4]; } yv;
        yv.u = ((const short4*)(Yp + (size_t)(s4 * CAP + g) * D_DIM))[tid];
        z0 += __bfloat162float(yv.h[0]);
        z1 += __bfloat162float(yv.h[1]);
        z2 += __bfloat162float(yv.h[2]);
        z3 += __bfloat162float(yv.h[3]);
    }

    float s = z0 + z1 + z2 + z3;
    float ss = z0 * z0 + z1 * z1 + z2 * z2 + z3 * z3;
#pragma unroll
    for (int off = 32; off > 0; off >>= 1) {
        s  += __shfl_down(s, off, 64);
        ss += __shfl_down(ss, off, 64);
    }
    __shared__ float red[4];
    int lane = tid & 63, wv = tid >> 6;
    if (lane == 0) { red[wv] = s; red[2 + wv] = ss; }
    __syncthreads();
    float S = red[0] + red[1];
    float SS = red[2] + red[3];
    float mu = S * (1.f / D_DIM);
    float var = SS * (1.f / D_DIM) - mu * mu;
    float inv = rsqrtf(var + 1e-5f);

    float4 gv = ((const float4*)gamma)[tid];
    float4 bv = ((const float4*)beta)[tid];
    float4 o;
    o.x = (z0 - mu) * inv * gv.x + bv.x;
    o.y = (z1 - mu) * inv * gv.y + bv.y;
    o.z = (z2 - mu) * inv * gv.z + bv.z;
    o.w = (z3 - mu) * inv * gv.w + bv.w;
    ((float4*)(out + (size_t)t * D_DIM))[tid] = o;
}

// ---------------------------------------------------------------------------
extern "C" void kernel_launch(void* const* d_in, const int* in_sizes, int n_in,
                              void* d_out, int out_size, void* d_ws, size_t ws_size,
                              hipStream_t stream)
{
    const float* x     = (const float*)d_in[0];
    const float* W1    = (const float*)d_in[1];
    const float* b1    = (const float*)d_in[2];
    const float* W2    = (const float*)d_in[3];
    const float* b2    = (const float*)d_in[4];
    const float* gamma = (const float*)d_in[5];
    const float* beta  = (const float*)d_in[6];
    const int* orig    = (const int*)d_in[7];
    const int* hmap    = (const int*)d_in[8];
    float* out = (float*)d_out;
    int ntok = in_sizes[7];   // B*S = 2048

    // Workspace layout (~34.1 MB)
    char* ws = (char*)d_ws;
    __hip_bfloat16* Yp  = (__hip_bfloat16*)(ws);             // [8][CAP][512] bf16, 20.97 MB
    __hip_bfloat16* Hb  = (__hip_bfloat16*)(ws + 20971520);  // [CAP][2048] bf16, 10.49 MB
    __hip_bfloat16* Xg  = (__hip_bfloat16*)(ws + 31457280);  // [CAP][512] bf16, 2.62 MB
    int*            gidx= (int*)(ws + 34078720);             // [CAP]
    int*            meta= (int*)(ws + 34088960);             // 32 ints

    hipLaunchKernelGGL(bin_kernel, dim3(1), dim3(1024), 0, stream,
                       orig, hmap, gidx, meta, ntok);
    hipLaunchKernelGGL(gather_kernel, dim3(CAP), dim3(128), 0, stream,
                       x, gidx, meta, Xg);
    // GEMM1: Xg[rows,512] x W1[E][512][2048] -> relu(+b1) -> bf16 Hb.
    // R19 grid (8 e, 1, 32 n): id%8 = e -> all 32 n-blocks of expert e are
    // co-XCD; Xg slice cached once in that XCD's L2 (~384 KB << 4 MB).
    hipLaunchKernelGGL((moe_gemm_kernel<H_DIM, D_DIM, D_DIM, 1, true>),
                       dim3(E_NUM, 1, H_DIM / 64), dim3(256), 0, stream,
                       Xg, W1, b1, Hb, (__hip_bfloat16*)nullptr, meta);
    // GEMM2: Hb[rows,2048] x W2[E][2048][512] -> bf16 partials (split-K=8).
    // R18 grid (8 ks, 8 n, 8 e): id%8 = ks -> the 8 n-blocks sharing an Hb
    // slice are co-XCD; slice cached once in that XCD's L2.
    hipLaunchKernelGGL((moe_gemm_kernel<D_DIM, H_DIM, H_DIM, 8, false>),
                       dim3(8, D_DIM / 64, E_NUM), dim3(256), 0, stream,
                       Hb, W2, (const float*)nullptr, (__hip_bfloat16*)nullptr, Yp, meta);
    hipLaunchKernelGGL(ln_kernel, dim3(CAP), dim3(128), 0, stream,
                       x, Yp, b2, gamma, beta, gidx, meta, out);
}